// Round 10
// baseline (213.435 us; speedup 1.0000x reference)
//
#include <hip/hip_runtime.h>
#include <hip/hip_bf16.h>
#include <stdint.h>

// B=16, N=4096, H=512, K=2H=1024
//   pf[b,n,h]   = sum_k features[b,n,k] * Wf[h,k]
//   pq[b,h]     = sum_k query[b,k] * Wq[h,k]
//   logits[b,n] = 10*tanh( sum_h v[h]*tanh(pf+pq) )
// Outputs: pf (33554432 f32) then logits (65536 f32).
// R10: m201-geometry GEMM (256x256 tile, BK=64, 8 waves 2x4, 128KB LDS dbuf,
// snake-quadrant phases x16 MFMA, stage-early + vmcnt(0)-late, setprio, LDS
// XOR-swizzle) fed by a streaming pass that pre-converts/pre-swizzles A and B
// into ws so all staging is linear global_load_lds. Rationale: R1-R9 invariant
// ~2.5us per sync step regardless of structure -> amortize with 2x MFMA/step
// and the proven schedule. u-reduction split over 2 N-blocks via ws partials.

#define KDIM 1024
#define HDIM 512

typedef short bf16x8 __attribute__((ext_vector_type(8)));
typedef float f32x4  __attribute__((ext_vector_type(4)));

__device__ __forceinline__ float fast_tanh(float x) {
    float ax = fabsf(x);
    float e  = __expf(-2.0f * ax);
    float r  = (1.0f - e) / (1.0f + e);
    return copysignf(r, x);
}

__device__ __forceinline__ short f2bf(float x) {
    __hip_bfloat16 b = __float2bfloat16(x);
    return (short)__builtin_bit_cast(unsigned short, b);
}

__device__ __forceinline__ bf16x8 cvt8(float4 a, float4 b) {
    bf16x8 o;
    o[0] = f2bf(a.x); o[1] = f2bf(a.y); o[2] = f2bf(a.z); o[3] = f2bf(a.w);
    o[4] = f2bf(b.x); o[5] = f2bf(b.y); o[6] = f2bf(b.z); o[7] = f2bf(b.w);
    return o;
}

// ---------------- pass 1a: features -> A_ws (bf16, tiled, pre-swizzled) ----
// A_ws layout: [mtile 256][kt 16][half 2][16384B half-tile]. Half-tile holds
// rows 0..127 x 64 k as [row][128B], with byte c holding source byte
// c ^ (((c>>9)&1)<<5)  (involution; GEMM ds_read applies the same XOR).
__global__ void acvt_kernel(const float* __restrict__ A, short* __restrict__ A_ws) {
    const int tid  = blockIdx.x * 256 + threadIdx.x;   // 8388608 chunks
    const int c    = tid & 1023;
    const int half = (tid >> 10) & 1;
    const int kt   = (tid >> 11) & 15;
    const int mt   = tid >> 15;
    const int cb   = c << 4;
    const int cs   = cb ^ (((cb >> 9) & 1) << 5);
    const int row  = cs >> 7;
    const int colb = cs & 127;
    const int grow = mt * 256 + half * 128 + row;
    const int k    = kt * 64 + (colb >> 1);
    const float* s = A + (size_t)grow * KDIM + k;
    float4 x = *(const float4*)s;
    float4 y = *(const float4*)(s + 4);
    *(bf16x8*)(A_ws + (size_t)tid * 8) = cvt8(x, y);
}

// ---------------- pass 1b: Wf -> B_ws (same tiling; row = output col) ------
__global__ void bshuf_kernel(const float* __restrict__ Wf, short* __restrict__ B_ws) {
    const int tid  = blockIdx.x * 256 + threadIdx.x;   // 65536 chunks
    const int c    = tid & 1023;
    const int half = (tid >> 10) & 1;
    const int kt   = (tid >> 11) & 15;
    const int nt   = tid >> 15;
    const int cb   = c << 4;
    const int cs   = cb ^ (((cb >> 9) & 1) << 5);
    const int row  = cs >> 7;
    const int colb = cs & 127;
    const int gcol = nt * 256 + half * 128 + row;
    const int k    = kt * 64 + (colb >> 1);
    const float* s = Wf + (size_t)gcol * KDIM + k;
    float4 x = *(const float4*)s;
    float4 y = *(const float4*)(s + 4);
    *(bf16x8*)(B_ws + (size_t)tid * 8) = cvt8(x, y);
}

// ---------------- tiny GEMM: pq[b,h] ----------------
__global__ void pq_kernel(const float* __restrict__ query,
                          const float* __restrict__ Wq,
                          float* __restrict__ pq) {
    const int t = blockIdx.x * blockDim.x + threadIdx.x;   // 8192
    const int b = t >> 9, h = t & 511;
    const float4* q  = (const float4*)(query + (b << 9));
    const float4* wq = (const float4*)(Wq + ((size_t)h << 9));
    float s = 0.0f;
    #pragma unroll 4
    for (int i = 0; i < 128; ++i) {
        float4 a = q[i], c = wq[i];
        s += a.x * c.x + a.y * c.y + a.z * c.z + a.w * c.w;
    }
    pq[t] = s;
}

// ---------------- main GEMM + fused epilogue ----------------
// grid (256 mtiles, 2 ntiles) x 512 thr (8 waves = 2m x 4n). Tile 256x256,
// BK=64, 16 K-tiles. Wave tile 128x64: acc[8][4] f32x4 = 128 AGPR.
__global__ __launch_bounds__(512, 2) void gemm_kernel(
    const short* __restrict__ A_ws, const short* __restrict__ B_ws,
    const float* __restrict__ pq, const float* __restrict__ v,
    float* __restrict__ pf, float* __restrict__ upart)
{
    __shared__ __align__(16) short ldsA[2][2][8192];   // [buf][half][128x64]
    __shared__ __align__(16) short ldsB[2][2][8192];
    __shared__ float uls[1024];                        // 256 rows x 4 wc
    const int t    = threadIdx.x;
    const int lane = t & 63;
    const int w    = t >> 6;
    const int wr   = w >> 2;        // m half: rows wr*128..+128
    const int wc   = w & 3;         // n quarter: cols wc*64..+64
    const int fm   = lane & 15;
    const int fkg  = lane >> 4;
    const int mt   = blockIdx.x;
    const int nt   = blockIdx.y;

    const char* Asrc = (const char*)A_ws + (size_t)mt * 524288;
    const char* Bsrc = (const char*)B_ws + (size_t)nt * 524288;

    // swizzle: colbyte ^= (row&4)<<3; row&4 == fm&4 for all frag rows.
    const int sx  = (fm & 4) << 3;
    const int ca0 = (fkg * 16) ^ sx;       // kk=0 colbyte; kk=1 = ca0+64
    const int brow0 = (wc & 1) * 64;       // B row base within half

    f32x4 acc[8][4];
    const f32x4 zf = {0.0f, 0.0f, 0.0f, 0.0f};
    #pragma unroll
    for (int f = 0; f < 8; ++f)
        #pragma unroll
        for (int g = 0; g < 4; ++g) acc[f][g] = zf;

    #define STAGE_A(BUF, KT) do {                                            \
        _Pragma("unroll")                                                    \
        for (int h_ = 0; h_ < 2; ++h_)                                       \
            _Pragma("unroll")                                                \
            for (int i_ = 0; i_ < 2; ++i_)                                   \
                __builtin_amdgcn_global_load_lds(                            \
                    (const __attribute__((address_space(1))) void*)          \
                        (Asrc + (KT) * 32768 + h_ * 16384 + (i_ * 512 + t) * 16), \
                    (__attribute__((address_space(3))) void*)                \
                        (((char*)&ldsA[BUF][h_][0]) + (i_ * 512 + t) * 16),  \
                    16, 0, 0);                                               \
    } while (0)

    #define STAGE_B(BUF, KT) do {                                            \
        _Pragma("unroll")                                                    \
        for (int h_ = 0; h_ < 2; ++h_)                                       \
            _Pragma("unroll")                                                \
            for (int i_ = 0; i_ < 2; ++i_)                                   \
                __builtin_amdgcn_global_load_lds(                            \
                    (const __attribute__((address_space(1))) void*)          \
                        (Bsrc + (KT) * 32768 + h_ * 16384 + (i_ * 512 + t) * 16), \
                    (__attribute__((address_space(3))) void*)                \
                        (((char*)&ldsB[BUF][h_][0]) + (i_ * 512 + t) * 16),  \
                    16, 0, 0);                                               \
    } while (0)

    bf16x8 aF[4][2], bF[2][2];

    // snake-quadrant phase: reads what changed, keeps the rest in regs.
    #define PHASE(F0, G0, RDA, RDB, STA, STB, VMW) do {                      \
        if (RDA) {                                                           \
            _Pragma("unroll")                                                \
            for (int fi = 0; fi < 4; ++fi) {                                 \
                const char* ab = Abase + (((F0) * 4 + fi) * 16 + fm) * 128;  \
                aF[fi][0] = *(const bf16x8*)(ab + ca0);                      \
                aF[fi][1] = *(const bf16x8*)(ab + ca0 + 64);                 \
            }                                                                \
        }                                                                    \
        if (RDB) {                                                           \
            _Pragma("unroll")                                                \
            for (int gi = 0; gi < 2; ++gi) {                                 \
                const char* bb = Bbase + (brow0 + ((G0) * 2 + gi) * 16 + fm) * 128; \
                bF[gi][0] = *(const bf16x8*)(bb + ca0);                      \
                bF[gi][1] = *(const bf16x8*)(bb + ca0 + 64);                 \
            }                                                                \
        }                                                                    \
        if ((STA) && kt < 15) STAGE_A(rb ^ 1, kt + 1);                       \
        if ((STB) && kt < 15) STAGE_B(rb ^ 1, kt + 1);                       \
        if (VMW) asm volatile("s_waitcnt vmcnt(0)" ::: "memory");            \
        asm volatile("" ::: "memory");                                       \
        __builtin_amdgcn_s_barrier();                                        \
        asm volatile("" ::: "memory");                                       \
        __builtin_amdgcn_s_setprio(1);                                       \
        _Pragma("unroll")                                                    \
        for (int fi = 0; fi < 4; ++fi)                                       \
            _Pragma("unroll")                                                \
            for (int gi = 0; gi < 2; ++gi)                                   \
                _Pragma("unroll")                                            \
                for (int kk = 0; kk < 2; ++kk)                               \
                    acc[(F0) * 4 + fi][(G0) * 2 + gi] =                      \
                        __builtin_amdgcn_mfma_f32_16x16x32_bf16(             \
                            aF[fi][kk], bF[gi][kk],                          \
                            acc[(F0) * 4 + fi][(G0) * 2 + gi], 0, 0, 0);     \
        __builtin_amdgcn_s_setprio(0);                                       \
        asm volatile("" ::: "memory");                                       \
        __builtin_amdgcn_s_barrier();                                        \
        asm volatile("" ::: "memory");                                       \
    } while (0)

    // prologue: tile 0 -> buf 0
    STAGE_A(0, 0);
    STAGE_B(0, 0);
    asm volatile("s_waitcnt vmcnt(0)" ::: "memory");
    __builtin_amdgcn_s_barrier();
    asm volatile("" ::: "memory");

    #pragma unroll 1
    for (int kt = 0; kt < 16; ++kt) {
        const int rb = kt & 1;
        const char* Abase = (const char*)&ldsA[rb][wr][0];
        const char* Bbase = (const char*)&ldsB[rb][wc >> 1][0];
        PHASE(0, 0, 1, 1, 1, 0, 0);   // q0: f0-3,g0-1; stage A(kt+1)
        PHASE(0, 1, 0, 1, 0, 1, 0);   // q1: f0-3,g2-3; stage B(kt+1)
        PHASE(1, 1, 1, 0, 0, 0, 0);   // q2: f4-7,g2-3
        PHASE(1, 0, 0, 1, 0, 0, 1);   // q3: f4-7,g0-1; wait tile kt+1
    }
    #undef PHASE
    #undef STAGE_A
    #undef STAGE_B

    // ---- fused epilogue: pf store + u partials ----
    const int Mbase = mt * 256;
    const int bidx  = Mbase >> 12;
    const float* pqb = pq + (bidx << 9);
    float vv[4], pv[4];
    #pragma unroll
    for (int g = 0; g < 4; ++g) {
        const int c = nt * 256 + wc * 64 + g * 16 + fm;
        vv[g] = v[c];
        pv[g] = pqb[c];
    }
    #pragma unroll
    for (int f = 0; f < 8; ++f) {
        #pragma unroll
        for (int rr = 0; rr < 4; ++rr) {
            const int rloc = wr * 128 + f * 16 + fkg * 4 + rr;
            float* prow = pf + (size_t)(Mbase + rloc) * HDIM
                             + nt * 256 + wc * 64 + fm;
            float s = 0.0f;
            #pragma unroll
            for (int g = 0; g < 4; ++g) {
                const float val = acc[f][g][rr];
                __builtin_nontemporal_store(val, &prow[g * 16]);
                s += vv[g] * fast_tanh(val + pv[g]);
            }
            s += __shfl_xor(s, 1);
            s += __shfl_xor(s, 2);
            s += __shfl_xor(s, 4);
            s += __shfl_xor(s, 8);
            if (fm == 0) uls[rloc * 4 + wc] = s;
        }
    }
    __syncthreads();
    if (t < 256) {
        const float4 p4 = *(const float4*)(uls + t * 4);
        upart[nt * 65536 + Mbase + t] = p4.x + p4.y + p4.z + p4.w;
    }
}

// ---------------- finish: logits = 10*tanh(sum of 2 nt partials) ----------
__global__ void finish_kernel(const float* __restrict__ upart,
                              float* __restrict__ logits) {
    const int i = blockIdx.x * blockDim.x + threadIdx.x;   // 65536
    logits[i] = 10.0f * fast_tanh(upart[i] + upart[65536 + i]);
}

extern "C" void kernel_launch(void* const* d_in, const int* in_sizes, int n_in,
                              void* d_out, int out_size, void* d_ws, size_t ws_size,
                              hipStream_t stream) {
    const float* features = (const float*)d_in[0];
    const float* query    = (const float*)d_in[1];
    const float* Wf       = (const float*)d_in[2];
    const float* Wq       = (const float*)d_in[3];
    const float* v        = (const float*)d_in[4];

    float* pf     = (float*)d_out;
    float* logits = (float*)d_out + 33554432;

    char* wsb    = (char*)d_ws;
    float* ws_pq = (float*)wsb;                        // 32 KB
    float* ws_up = (float*)(wsb + 32768);              // 512 KB (2 x 65536 f32)
    short* B_ws  = (short*)(wsb + 557056);             // 1 MB
    short* A_ws  = (short*)(wsb + 1605632);            // 134 MB

    acvt_kernel<<<32768, 256, 0, stream>>>(features, A_ws);
    bshuf_kernel<<<256, 256, 0, stream>>>(Wf, B_ws);
    pq_kernel<<<16, 512, 0, stream>>>(query, Wq, ws_pq);
    gemm_kernel<<<dim3(256, 2), 512, 0, stream>>>(A_ws, B_ws, ws_pq, v, pf, ws_up);
    finish_kernel<<<256, 256, 0, stream>>>(ws_up, logits);
}

// Round 11
// 210.979 us; speedup vs baseline: 1.0116x; 1.0116x over previous
//
#include <hip/hip_runtime.h>
#include <hip/hip_bf16.h>
#include <stdint.h>

// B=16, N=4096, H=512, K=2H=1024
//   pf[b,n,h]   = sum_k features[b,n,k] * Wf[h,k]
//   pq[b,h]     = sum_k query[b,k] * Wq[h,k]
//   logits[b,n] = 10*tanh( sum_h v[h]*tanh(pf+pq) )
// Outputs: pf (33554432 f32) then logits (65536 f32).
// R11: minimize barrier-intervals (R1-R10 invariant: T ~ gens*steps*6600cy/OV).
// 256x256 tile, BK=64, 128KB LDS dbuf, 512 blocks = 2 gens x 16 steps = 32
// intervals/CU (vs 64-85 in R1-R10). A pre-converted bf16 + B pre-shuffled,
// BOTH in MFMA-fragment chunk order -> all gll linear, all ds_read conflict-
// free, no swizzle. Phase = [vmcnt(4); s_barrier; ds_read; stage-half; 
// setprio1; 32 MFMA; setprio0] -- uniform counted vmcnt(4) provably waits the
// 2-phase-old half-tile (batch accounting: newer batches = exactly 1 x 4 ops).

#define KDIM 1024
#define HDIM 512

typedef short bf16x8 __attribute__((ext_vector_type(8)));
typedef float f32x4  __attribute__((ext_vector_type(4)));

__device__ __forceinline__ float fast_tanh(float x) {
    float ax = fabsf(x);
    float e  = __expf(-2.0f * ax);
    float r  = (1.0f - e) / (1.0f + e);
    return copysignf(r, x);
}

__device__ __forceinline__ short f2bf(float x) {
    __hip_bfloat16 b = __float2bfloat16(x);
    return (short)__builtin_bit_cast(unsigned short, b);
}

__device__ __forceinline__ bf16x8 cvt8(float4 a, float4 b) {
    bf16x8 o;
    o[0] = f2bf(a.x); o[1] = f2bf(a.y); o[2] = f2bf(a.z); o[3] = f2bf(a.w);
    o[4] = f2bf(b.x); o[5] = f2bf(b.y); o[6] = f2bf(b.z); o[7] = f2bf(b.w);
    return o;
}

// ---------------- pass 1a: features -> A_ws (bf16, fragment-chunk order) ---
// A_ws: [mb 256][s 16][h 2][1024 chunks x 16B]. chunk c = (wr*8+f)*64+lane,
// lane = fkg*16+fm: content = A[mb*256+wr*128+f*16+fm][s*64+h*32+fkg*8 ..+8].
__global__ void acvt_kernel(const float* __restrict__ A, short* __restrict__ A_ws) {
    const int tid  = blockIdx.x * 256 + threadIdx.x;   // 8,388,608 chunks
    const int lane = tid & 63;
    const int f    = (tid >> 6) & 7;
    const int wr   = (tid >> 9) & 1;
    const int h    = (tid >> 10) & 1;
    const int s    = (tid >> 11) & 15;
    const int mb   = tid >> 15;
    const int fm   = lane & 15, fkg = lane >> 4;
    const int row  = mb * 256 + wr * 128 + f * 16 + fm;
    const int k    = s * 64 + h * 32 + fkg * 8;
    const float* src = A + (size_t)row * KDIM + k;
    float4 a = *(const float4*)src;
    float4 b = *(const float4*)(src + 4);
    *(bf16x8*)(A_ws + (size_t)tid * 8) = cvt8(a, b);
}

// ---------------- pass 1b: Wf -> B_ws (bf16, fragment-chunk order) ---------
// B_ws: [nb 2][s 16][h 2][1024 chunks]. chunk c = (wc*4+g)*64+lane:
// content = Wf[nb*256+wc*64+g*16+fm][s*64+h*32+fkg*8 ..+8].
__global__ void bshuf_kernel(const float* __restrict__ Wf, short* __restrict__ B_ws) {
    const int tid  = blockIdx.x * 256 + threadIdx.x;   // 65536 chunks
    const int lane = tid & 63;
    const int g    = (tid >> 6) & 3;
    const int wc   = (tid >> 8) & 3;
    const int h    = (tid >> 10) & 1;
    const int s    = (tid >> 11) & 15;
    const int nb   = (tid >> 15) & 1;
    const int fm   = lane & 15, fkg = lane >> 4;
    const int col  = nb * 256 + wc * 64 + g * 16 + fm;
    const int k    = s * 64 + h * 32 + fkg * 8;
    const float* src = Wf + (size_t)col * KDIM + k;
    float4 a = *(const float4*)src;
    float4 b = *(const float4*)(src + 4);
    *(bf16x8*)(B_ws + (size_t)tid * 8) = cvt8(a, b);
}

// ---------------- tiny GEMM: pq[b,h] ----------------
__global__ void pq_kernel(const float* __restrict__ query,
                          const float* __restrict__ Wq,
                          float* __restrict__ pq) {
    const int t = blockIdx.x * blockDim.x + threadIdx.x;   // 8192
    const int b = t >> 9, h = t & 511;
    const float4* q  = (const float4*)(query + (b << 9));
    const float4* wq = (const float4*)(Wq + ((size_t)h << 9));
    float s = 0.0f;
    #pragma unroll 4
    for (int i = 0; i < 128; ++i) {
        float4 a = q[i], c = wq[i];
        s += a.x * c.x + a.y * c.y + a.z * c.z + a.w * c.w;
    }
    pq[t] = s;
}

// ---------------- main GEMM + fused epilogue ----------------
// grid (2 nb, 256 mb) x 512 thr (8 waves = 2wr x 4wc). Tile 256x256, BK=64,
// 16 K-steps x 2 phases (k=32 each). Wave tile 128x64: acc[8][4] = 128 AGPR.
__global__ __launch_bounds__(512, 2) void gemm_kernel(
    const short* __restrict__ A_ws, const short* __restrict__ B_ws,
    const float* __restrict__ pq, const float* __restrict__ v,
    float* __restrict__ pf, float* __restrict__ upart)
{
    __shared__ __align__(16) char ldsA[2][2][16384];   // [buf][half][16KB]
    __shared__ __align__(16) char ldsB[2][2][16384];
    __shared__ float uls[1024];                        // 256 rows x 4 wc
    const int t    = threadIdx.x;
    const int lane = t & 63;
    const int w    = t >> 6;
    const int wr   = w >> 2;        // rows wr*128..+128
    const int wc   = w & 3;         // cols wc*64..+64
    const int fm   = lane & 15;
    const int fkg  = lane >> 4;
    const int nb   = blockIdx.x;
    const int mb   = blockIdx.y;

    const char* Asrc = (const char*)A_ws + (size_t)mb * 524288;   // 16*2*16KB
    const char* Bsrc = (const char*)B_ws + (size_t)nb * 524288;

    f32x4 acc[8][4];
    const f32x4 zf = {0.0f, 0.0f, 0.0f, 0.0f};
    #pragma unroll
    for (int f = 0; f < 8; ++f)
        #pragma unroll
        for (int g = 0; g < 4; ++g) acc[f][g] = zf;

    // stage half PH of step SN into buf BUF: 2 A-chunks + 2 B-chunks per thread
    #define STAGE(BUF, SN, PH) do {                                          \
        const char* as_ = Asrc + (((SN) * 2 + (PH)) << 14);                  \
        const char* bs_ = Bsrc + (((SN) * 2 + (PH)) << 14);                  \
        _Pragma("unroll")                                                    \
        for (int i_ = 0; i_ < 2; ++i_)                                       \
            __builtin_amdgcn_global_load_lds(                                \
                (const __attribute__((address_space(1))) void*)              \
                    (as_ + (i_ * 512 + t) * 16),                             \
                (__attribute__((address_space(3))) void*)                    \
                    (&ldsA[BUF][PH][(i_ * 512 + t) * 16]), 16, 0, 0);        \
        _Pragma("unroll")                                                    \
        for (int i_ = 0; i_ < 2; ++i_)                                       \
            __builtin_amdgcn_global_load_lds(                                \
                (const __attribute__((address_space(1))) void*)              \
                    (bs_ + (i_ * 512 + t) * 16),                             \
                (__attribute__((address_space(3))) void*)                    \
                    (&ldsB[BUF][PH][(i_ * 512 + t) * 16]), 16, 0, 0);        \
    } while (0)

    // phase: vmcnt(4) waits the 2-phase-old half; barrier makes it collective;
    // ds_read current half; stage same half of next step into other buf; MFMA.
    #define PHASE(S, PH) do {                                                \
        asm volatile("s_waitcnt vmcnt(4)" ::: "memory");                     \
        __builtin_amdgcn_s_barrier();                                        \
        asm volatile("" ::: "memory");                                       \
        const char* ab = &ldsA[(S) & 1][PH][0];                              \
        const char* bb = &ldsB[(S) & 1][PH][0];                              \
        bf16x8 aF[8], bF[4];                                                 \
        _Pragma("unroll")                                                    \
        for (int f = 0; f < 8; ++f)                                          \
            aF[f] = *(const bf16x8*)(ab + ((wr * 8 + f) << 10) + (lane << 4)); \
        _Pragma("unroll")                                                    \
        for (int g = 0; g < 4; ++g)                                          \
            bF[g] = *(const bf16x8*)(bb + ((wc * 4 + g) << 10) + (lane << 4)); \
        STAGE(((S) + 1) & 1, ((S) + 1) & 15, PH);                            \
        __builtin_amdgcn_s_setprio(1);                                       \
        _Pragma("unroll")                                                    \
        for (int f = 0; f < 8; ++f)                                          \
            _Pragma("unroll")                                                \
            for (int g = 0; g < 4; ++g)                                      \
                acc[f][g] = __builtin_amdgcn_mfma_f32_16x16x32_bf16(         \
                    aF[f], bF[g], acc[f][g], 0, 0, 0);                       \
        __builtin_amdgcn_s_setprio(0);                                       \
        asm volatile("" ::: "memory");                                       \
    } while (0)

    // prologue: stage step 0 fully into buf 0, drain once.
    STAGE(0, 0, 0);
    STAGE(0, 0, 1);
    asm volatile("s_waitcnt vmcnt(0)" ::: "memory");
    __builtin_amdgcn_s_barrier();
    asm volatile("" ::: "memory");

    #pragma unroll 1
    for (int s = 0; s < 16; ++s) {
        PHASE(s, 0);
        PHASE(s, 1);
    }
    #undef PHASE
    #undef STAGE

    // ---- fused epilogue: pf store + u partials ----
    const int Mbase = mb * 256;
    const int bidx  = Mbase >> 12;
    const float* pqb = pq + (bidx << 9);
    float vv[4], pv[4];
    #pragma unroll
    for (int g = 0; g < 4; ++g) {
        const int c = nb * 256 + wc * 64 + g * 16 + fm;
        vv[g] = v[c];
        pv[g] = pqb[c];
    }
    #pragma unroll
    for (int f = 0; f < 8; ++f) {
        #pragma unroll
        for (int rr = 0; rr < 4; ++rr) {
            const int rloc = wr * 128 + f * 16 + fkg * 4 + rr;
            float* prow = pf + (size_t)(Mbase + rloc) * HDIM
                             + nb * 256 + wc * 64 + fm;
            float s = 0.0f;
            #pragma unroll
            for (int g = 0; g < 4; ++g) {
                const float val = acc[f][g][rr];
                __builtin_nontemporal_store(val, &prow[g * 16]);
                s += vv[g] * fast_tanh(val + pv[g]);
            }
            s += __shfl_xor(s, 1);
            s += __shfl_xor(s, 2);
            s += __shfl_xor(s, 4);
            s += __shfl_xor(s, 8);
            if (fm == 0) uls[rloc * 4 + wc] = s;
        }
    }
    __syncthreads();
    if (t < 256) {
        const float4 p4 = *(const float4*)(uls + t * 4);
        upart[nb * 65536 + Mbase + t] = p4.x + p4.y + p4.z + p4.w;
    }
}

// ---------------- finish: logits = 10*tanh(sum of 2 nb partials) ----------
__global__ void finish_kernel(const float* __restrict__ upart,
                              float* __restrict__ logits) {
    const int i = blockIdx.x * blockDim.x + threadIdx.x;   // 65536
    logits[i] = 10.0f * fast_tanh(upart[i] + upart[65536 + i]);
}

extern "C" void kernel_launch(void* const* d_in, const int* in_sizes, int n_in,
                              void* d_out, int out_size, void* d_ws, size_t ws_size,
                              hipStream_t stream) {
    const float* features = (const float*)d_in[0];
    const float* query    = (const float*)d_in[1];
    const float* Wf       = (const float*)d_in[2];
    const float* Wq       = (const float*)d_in[3];
    const float* v        = (const float*)d_in[4];

    float* pf     = (float*)d_out;
    float* logits = (float*)d_out + 33554432;

    char* wsb    = (char*)d_ws;
    float* ws_pq = (float*)wsb;                        // 32 KB
    float* ws_up = (float*)(wsb + 32768);              // 512 KB (2 x 65536 f32)
    short* B_ws  = (short*)(wsb + 557056);             // 1 MB
    short* A_ws  = (short*)(wsb + 1605632);            // 134 MB (proven in R10)

    acvt_kernel<<<32768, 256, 0, stream>>>(features, A_ws);
    bshuf_kernel<<<256, 256, 0, stream>>>(Wf, B_ws);
    pq_kernel<<<16, 512, 0, stream>>>(query, Wq, ws_pq);
    gemm_kernel<<<dim3(2, 256), 512, 0, stream>>>(A_ws, B_ws, ws_pq, v, pf, ws_up);
    finish_kernel<<<256, 256, 0, stream>>>(ws_up, logits);
}

// Round 12
// 190.858 us; speedup vs baseline: 1.1183x; 1.1054x over previous
//
#include <hip/hip_runtime.h>
#include <hip/hip_bf16.h>
#include <stdint.h>

// B=16, N=4096, H=512, K=2H=1024
//   pf[b,n,h]   = sum_k features[b,n,k] * Wf[h,k]
//   pq[b,h]     = sum_k query[b,k] * Wq[h,k]
//   logits[b,n] = 10*tanh( sum_h v[h]*tanh(pf+pq) )
// Outputs: pf (33554432 f32) then logits (65536 f32).
// R12: high co-residency + uniform queue deadlines (the combo no prior round
// had). 32x512 tile, 4 waves n-split, acc 64 AGPR + ~103 VGPR -> lb(256,3):
// 3 blocks/CU, 12 waves/CU (m97-class overlap). Per step ONE vmcnt(9) + ONE
// barrier: A via gll into mod-4 LDS slots staged AFTER the barrier (race-free:
// all waves past barrier kt => step kt-1 reads consumed); B reg-sets loaded
// 2 steps ahead, issued AFTER the MFMA (WAR on the just-consumed set), so
// both streams have >=2-step slack in one monotone counter -- waiting B(kt)
// never drains anything younger than 2 steps. B from fragment-order ws
// (L2-resident); A fp32 cvt-on-read (1x/element).

#define KDIM 1024
#define HDIM 512

typedef short bf16x8 __attribute__((ext_vector_type(8)));
typedef float f32x4  __attribute__((ext_vector_type(4)));

__device__ __forceinline__ float fast_tanh(float x) {
    float ax = fabsf(x);
    float e  = __expf(-2.0f * ax);
    float r  = (1.0f - e) / (1.0f + e);
    return copysignf(r, x);
}

__device__ __forceinline__ short f2bf(float x) {
    __hip_bfloat16 b = __float2bfloat16(x);
    return (short)__builtin_bit_cast(unsigned short, b);
}

__device__ __forceinline__ bf16x8 cvt8(float4 a, float4 b) {
    bf16x8 o;
    o[0] = f2bf(a.x); o[1] = f2bf(a.y); o[2] = f2bf(a.z); o[3] = f2bf(a.w);
    o[4] = f2bf(b.x); o[5] = f2bf(b.y); o[6] = f2bf(b.z); o[7] = f2bf(b.w);
    return o;
}

// ---------------- Wf -> bf16 B-fragment order (proven R4-R8) ----------------
// chunk tid = (kt*32 + gg)*64 + lane, lane = fkg*16+fm:
// content = Wf[gg*16+fm][kt*32 + fkg*8 .. +8] as bf16x8.
__global__ void bshuf_kernel(const float* __restrict__ Wf, short* __restrict__ Bsh) {
    const int tid = blockIdx.x * 256 + threadIdx.x;   // 0..65535
    const int kt  = tid >> 11;
    const int gg  = (tid >> 6) & 31;
    const int ln  = tid & 63;
    const int fm  = ln & 15, fkg = ln >> 4;
    const int col = gg * 16 + fm;
    const int k0  = kt * 32 + fkg * 8;
    const float* src = Wf + col * KDIM + k0;
    float4 a = *(const float4*)src;
    float4 b = *(const float4*)(src + 4);
    *(bf16x8*)(Bsh + (size_t)tid * 8) = cvt8(a, b);
}

// ---------------- tiny GEMM: pq[b,h] ----------------
__global__ void pq_kernel(const float* __restrict__ query,
                          const float* __restrict__ Wq,
                          float* __restrict__ pq) {
    const int t = blockIdx.x * blockDim.x + threadIdx.x;   // 8192
    const int b = t >> 9, h = t & 511;
    const float4* q  = (const float4*)(query + (b << 9));
    const float4* wq = (const float4*)(Wq + ((size_t)h << 9));
    float s = 0.0f;
    #pragma unroll 4
    for (int i = 0; i < 128; ++i) {
        float4 a = q[i], c = wq[i];
        s += a.x * c.x + a.y * c.y + a.z * c.z + a.w * c.w;
    }
    pq[t] = s;
}

// ---------------- main GEMM + fused epilogue ----------------
// 2048 blocks x 256 thr (4 waves, n-split). Tile 32x512, wave 32x128, BK=32.
__global__ __launch_bounds__(256, 3) void gemm_kernel(
    const float* __restrict__ A, const short* __restrict__ Bsh,
    const float* __restrict__ pq, const float* __restrict__ v,
    float* __restrict__ pf, float* __restrict__ logits)
{
    __shared__ __align__(16) char ldsA[4][4096];   // mod-4 slots, 32 rows x 128B
    __shared__ float uls[128];                     // 32 rows x 4 waves
    const int t    = threadIdx.x;
    const int lane = t & 63;
    const int w    = t >> 6;          // wave -> cols w*128..+128
    const int fm   = lane & 15;
    const int fkg  = lane >> 4;       // 0..3
    const int Mbase = blockIdx.x * 32;

    // A staging: thread t fills LDS chunk t from inverse-swizzled source:
    // LDS(row, sp) holds global (row, sp ^ (row&7)); 16B chunks.
    const int srow = t >> 3, sp = t & 7;
    const int asrc = srow * 4096 + ((sp ^ (srow & 7)) << 4);
    const char* Ab = (const char*)(A + (size_t)Mbase * KDIM);

    // A fragment ds_read offsets (swizzled): rows {fm, fm+16}, slots fkg*2,+1
    int ard[2][2];
    #pragma unroll
    for (int f = 0; f < 2; ++f) {
        const int r = f * 16 + fm;
        ard[f][0] = r * 128 + (((fkg * 2    ) ^ (r & 7)) << 4);
        ard[f][1] = r * 128 + (((fkg * 2 + 1) ^ (r & 7)) << 4);
    }

    // B fragment base (fragment-order ws): chunk (w*8+g)*64+lane, kt*32KB
    const char* Bb = (const char*)Bsh + (size_t)(w * 8 * 64 + lane) * 16;

    f32x4 acc[2][8];
    const f32x4 zf = {0.0f, 0.0f, 0.0f, 0.0f};
    #pragma unroll
    for (int f = 0; f < 2; ++f)
        #pragma unroll
        for (int g = 0; g < 8; ++g) acc[f][g] = zf;

    bf16x8 b0[8], b1[8];

    #define STAGE(SLOT, KS) \
        __builtin_amdgcn_global_load_lds( \
            (const __attribute__((address_space(1))) void*)(Ab + asrc + ((KS) & 31) * 128), \
            (__attribute__((address_space(3))) void*)(&ldsA[SLOT][t * 16]), 16, 0, 0)

    #define LOADB(SET, KT) do {                                              \
        const char* bk_ = Bb + (size_t)((KT) & 31) * 32768;                  \
        _Pragma("unroll")                                                    \
        for (int g = 0; g < 8; ++g)                                          \
            SET[g] = *(const bf16x8*)(bk_ + g * 1024);                       \
    } while (0)

    // Step kt: [vmcnt(W); barrier] -> [stage A(kt+3) post-barrier (race-free)]
    // -> ds_read A(kt) -> cvt -> 16 MFMA with B-set(kt) -> load B(kt+2) into
    // the just-consumed set (WAR keeps queue order: gll before B-loads).
    #define STEP(KT, BC, WAITN) do {                                         \
        asm volatile("s_waitcnt vmcnt(" #WAITN ")" ::: "memory");            \
        __builtin_amdgcn_s_barrier();                                        \
        asm volatile("" ::: "memory");                                       \
        STAGE(((KT) + 3) & 3, (KT) + 3);                                     \
        const char* base = ldsA[(KT) & 3];                                   \
        float4 ra0 = *(const float4*)(base + ard[0][0]);                     \
        float4 ra1 = *(const float4*)(base + ard[0][1]);                     \
        float4 ra2 = *(const float4*)(base + ard[1][0]);                     \
        float4 ra3 = *(const float4*)(base + ard[1][1]);                     \
        bf16x8 a0 = cvt8(ra0, ra1);                                          \
        bf16x8 a1 = cvt8(ra2, ra3);                                          \
        __builtin_amdgcn_s_setprio(1);                                       \
        _Pragma("unroll")                                                    \
        for (int g = 0; g < 8; ++g)                                          \
            acc[0][g] = __builtin_amdgcn_mfma_f32_16x16x32_bf16(             \
                a0, BC[g], acc[0][g], 0, 0, 0);                              \
        _Pragma("unroll")                                                    \
        for (int g = 0; g < 8; ++g)                                          \
            acc[1][g] = __builtin_amdgcn_mfma_f32_16x16x32_bf16(             \
                a1, BC[g], acc[1][g], 0, 0, 0);                              \
        __builtin_amdgcn_s_setprio(0);                                       \
        LOADB(BC, (KT) + 2);                                                 \
    } while (0)

    // prologue: A slots 0-2 staged; B sets 0-1 loaded. Queue: A0 A1 A2 B0 B1.
    STAGE(0, 0);
    STAGE(1, 1);
    STAGE(2, 2);
    LOADB(b0, 0);
    LOADB(b1, 1);

    STEP(0, b0, 8);                    // newer-than-B0 = B1(8)
    #pragma unroll 1
    for (int kt2 = 0; kt2 < 15; ++kt2) {
        STEP(2 * kt2 + 1, b1, 9);      // newer-than-B(kt) = A(kt+2)+B(kt+1) = 9
        STEP(2 * kt2 + 2, b0, 9);
    }
    STEP(31, b1, 9);
    #undef STEP
    #undef STAGE
    #undef LOADB

    // ---- fused epilogue: pf store + u partials ----
    const int bidx = Mbase >> 12;
    const float* pqb = pq + (bidx << 9);
    float vv[8], pv[8];
    #pragma unroll
    for (int g = 0; g < 8; ++g) {
        const int c = w * 128 + g * 16 + fm;
        vv[g] = v[c];
        pv[g] = pqb[c];
    }
    #pragma unroll
    for (int f = 0; f < 2; ++f) {
        #pragma unroll
        for (int rr = 0; rr < 4; ++rr) {
            const int rloc = f * 16 + fkg * 4 + rr;
            float* prow = pf + (size_t)(Mbase + rloc) * HDIM + w * 128 + fm;
            float s = 0.0f;
            #pragma unroll
            for (int g = 0; g < 8; ++g) {
                const float val = acc[f][g][rr];
                __builtin_nontemporal_store(val, &prow[g * 16]);
                s += vv[g] * fast_tanh(val + pv[g]);
            }
            s += __shfl_xor(s, 1);
            s += __shfl_xor(s, 2);
            s += __shfl_xor(s, 4);
            s += __shfl_xor(s, 8);
            if (fm == 0) uls[rloc * 4 + w] = s;
        }
    }
    __syncthreads();
    if (t < 32) {
        const float4 p4 = *(const float4*)(uls + t * 4);
        const float u = p4.x + p4.y + p4.z + p4.w;
        logits[Mbase + t] = 10.0f * fast_tanh(u);
    }
}

extern "C" void kernel_launch(void* const* d_in, const int* in_sizes, int n_in,
                              void* d_out, int out_size, void* d_ws, size_t ws_size,
                              hipStream_t stream) {
    const float* features = (const float*)d_in[0];
    const float* query    = (const float*)d_in[1];
    const float* Wf       = (const float*)d_in[2];
    const float* Wq       = (const float*)d_in[3];
    const float* v        = (const float*)d_in[4];

    float* pf     = (float*)d_out;
    float* logits = (float*)d_out + 33554432;

    float* ws_pq  = (float*)d_ws;                    // 8192 f32  (32KB)
    short* ws_bsh = (short*)(ws_pq + 8192);          // 524288 bf16 (1MB)

    bshuf_kernel<<<256, 256, 0, stream>>>(Wf, ws_bsh);
    pq_kernel<<<16, 512, 0, stream>>>(query, Wq, ws_pq);
    gemm_kernel<<<2048, 256, 0, stream>>>(features, ws_bsh, ws_pq, v, pf, logits);
}